// Round 16
// 557.076 us; speedup vs baseline: 5.9241x; 1.0515x over previous
//
#include <hip/hip_runtime.h>
#include <hip/hip_bf16.h>
#include <math.h>

#define NEG_SLOPE 0.2f

// ---------------- utility ----------------
__global__ void zero_i32(int* __restrict__ p, int n) {
    int i = blockIdx.x * blockDim.x + threadIdx.x;
    if (i < n) p[i] = 0;
}

// ---------------- CSR build (both branches in one dispatch) ----------------
__global__ void count_edges2(const int* __restrict__ dst0, const int* __restrict__ dst1,
                             int* __restrict__ cnt, int N, int E) {
    int i = blockIdx.x * blockDim.x + threadIdx.x;
    if (i >= 2 * E) return;
    int br = i >= E;
    int j = i - br * E;
    const int* d = br ? dst1 : dst0;
    atomicAdd(&cnt[br * N + d[j]], 1);
}

// scan + zero cnt in place (cnt reused as fill[] by scatter afterwards)
__global__ void scan_block(int* __restrict__ cnt_all, int* __restrict__ rs_all, int N) {
    __shared__ int s[1024];
    int br = blockIdx.x;
    int* cnt = cnt_all + br * N;
    int* rs = rs_all + br * (N + 1);
    int tid = threadIdx.x;
    int running = 0;
    for (int base = 0; base < N; base += 1024) {
        int v = (base + tid < N) ? cnt[base + tid] : 0;
        if (base + tid < N) cnt[base + tid] = 0;
        __syncthreads();
        s[tid] = v;
        __syncthreads();
        for (int off = 1; off < 1024; off <<= 1) {
            int t = (tid >= off) ? s[tid - off] : 0;
            __syncthreads();
            if (tid >= off) s[tid] += t;
            __syncthreads();
        }
        if (base + tid < N) rs[base + tid] = running + s[tid] - v;
        running += s[1023];
    }
    if (tid == 0) rs[N] = running;
}

__global__ void scatter_edges2(const int* __restrict__ dst0, const int* __restrict__ dst1,
                               const int* __restrict__ rs_all, int* __restrict__ fill_all,
                               int* __restrict__ eidx_all, int N, int E) {
    int i = blockIdx.x * blockDim.x + threadIdx.x;
    if (i >= 2 * E) return;
    int br = i >= E;
    int j = i - br * E;
    const int* d = br ? dst1 : dst0;
    int dd = d[j];
    int pos = atomicAdd(&fill_all[br * N + dd], 1);
    eidx_all[br * E + rs_all[br * (N + 1) + dd] + pos] = j;
}

// ---------------- bf16 hi/lo helpers ----------------
__device__ __forceinline__ short f2bf(float x) {
    __hip_bfloat16 h = __float2bfloat16(x);
    return *reinterpret_cast<short*>(&h);
}
__device__ __forceinline__ float bf2f(short s) {
    unsigned int u = ((unsigned int)(unsigned short)s) << 16;
    return __uint_as_float(u);
}
__device__ __forceinline__ float us2f(unsigned short s) {
    return __uint_as_float((unsigned int)s << 16);
}

// ---------------- merged weight prep (all 6 splits, one dispatch) -----------
__device__ __forceinline__ void split_w_elem(const float* W, short* W2t, int K, int N, int idx) {
    int k = idx / N, n = idx - k * N;
    float x = W[idx];
    short hs = f2bf(x);
    short ls = f2bf(x - bf2f(hs));
    size_t base = (size_t)n * 2 * K;
    W2t[base + k] = hs;
    W2t[base + K + k] = ls;
}
__device__ __forceinline__ void split_cw_elem(const float* w, short* w2, int Kp, int idx) {
    int o = idx / Kp, k = idx - o * Kp;
    float x = w[idx];
    short hs = f2bf(x);
    short ls = f2bf(x - bf2f(hs));
    size_t base = (size_t)o * 2 * Kp;
    w2[base + k] = hs;
    w2[base + Kp + k] = ls;
}
__global__ void prep_weights(const float* __restrict__ Wg1, const float* __restrict__ Wg2,
                             const float* __restrict__ Wg3, const float* __restrict__ c1w,
                             const float* __restrict__ c2w, const float* __restrict__ c3w,
                             short* __restrict__ w2t1, short* __restrict__ w2t2,
                             short* __restrict__ w2t3, short* __restrict__ cw1,
                             short* __restrict__ cw2, short* __restrict__ cw3) {
    int idx = blockIdx.x * blockDim.x + threadIdx.x;
    if (idx < 12288)       split_w_elem(Wg1, w2t1, 64, 192, idx);
    else if (idx < 122880) split_w_elem(Wg2, w2t2, 192, 576, idx - 12288);
    else if (idx < 454656) split_w_elem(Wg3, w2t3, 576, 576, idx - 122880);
    else if (idx < 479232) split_cw_elem(c1w, cw1, 192, idx - 454656);
    else if (idx < 528384) split_cw_elem(c2w, cw2, 384, idx - 479232);
    else if (idx < 577536) split_cw_elem(c3w, cw3, 384, idx - 528384);
}

// ---------------- MFMA bf16-split GEMM v4 (bf16-only output) ----------------
typedef __attribute__((ext_vector_type(8))) short short8;
typedef __attribute__((ext_vector_type(4))) short short4v;
typedef __attribute__((ext_vector_type(4))) float floatx4;

__global__ __launch_bounds__(256) void gemm_bf3_v4(const float* __restrict__ A0,
                                                   const float* __restrict__ A1,
                                                   const short* __restrict__ Bt,
                                                   unsigned short* __restrict__ Cbf,
                                                   int M, int K, int N, size_t cBrStride) {
    __shared__ __align__(16) short sA[64 * 72];
    __shared__ __align__(16) short sB[192 * 72];
    int tid = threadIdx.x;
    int wave = tid >> 6, lane = tid & 63;
    int m = lane & 15, q = lane >> 4;
    int row0 = blockIdx.y << 6;
    int col0 = blockIdx.x * 192;
    const float* A = blockIdx.z ? A1 : A0;
    unsigned short* Cbfb = Cbf + blockIdx.z * cBrStride;
    int K2 = K * 2;
    floatx4 acc[4][3];
#pragma unroll
    for (int rt = 0; rt < 4; ++rt)
#pragma unroll
        for (int ct = 0; ct < 3; ++ct) acc[rt][ct] = (floatx4){0.f, 0.f, 0.f, 0.f};

    for (int k0 = 0; k0 < K; k0 += 32) {
#pragma unroll
        for (int p = 0; p < 2; ++p) {
            int t = tid + (p << 8);
            int r = t >> 3, c = (t & 7) << 2;
            float4 av = *(const float4*)&A[(size_t)(row0 + r) * K + k0 + c];
            short4v hs, ls;
            hs[0] = f2bf(av.x); ls[0] = f2bf(av.x - bf2f(hs[0]));
            hs[1] = f2bf(av.y); ls[1] = f2bf(av.y - bf2f(hs[1]));
            hs[2] = f2bf(av.z); ls[2] = f2bf(av.z - bf2f(hs[2]));
            hs[3] = f2bf(av.w); ls[3] = f2bf(av.w - bf2f(hs[3]));
            *(short4v*)&sA[r * 72 + c] = hs;
            *(short4v*)&sA[r * 72 + 32 + c] = ls;
        }
#pragma unroll
        for (int p = 0; p < 6; ++p) {
            int t = tid + (p << 8);
            int n = t >> 3, sub = t & 7;
            int srcoff = k0 + (sub << 3) + ((sub >= 4) ? (K - 32) : 0);
            *(float4*)&sB[n * 72 + (sub << 3)] =
                *(const float4*)&Bt[(size_t)(col0 + n) * K2 + srcoff];
        }
        __syncthreads();
        short8 a_hi[4], a_lo[4];
#pragma unroll
        for (int rt = 0; rt < 4; ++rt) {
            a_hi[rt] = *(const short8*)&sA[(rt * 16 + m) * 72 + q * 8];
            a_lo[rt] = *(const short8*)&sA[(rt * 16 + m) * 72 + 32 + q * 8];
        }
#pragma unroll
        for (int ct = 0; ct < 3; ++ct) {
            short8 b_hi = *(const short8*)&sB[(wave * 48 + ct * 16 + m) * 72 + q * 8];
            short8 b_lo = *(const short8*)&sB[(wave * 48 + ct * 16 + m) * 72 + 32 + q * 8];
#pragma unroll
            for (int rt = 0; rt < 4; ++rt) {
                acc[rt][ct] = __builtin_amdgcn_mfma_f32_16x16x32_bf16(a_hi[rt], b_hi, acc[rt][ct], 0, 0, 0);
                acc[rt][ct] = __builtin_amdgcn_mfma_f32_16x16x32_bf16(a_lo[rt], b_hi, acc[rt][ct], 0, 0, 0);
                acc[rt][ct] = __builtin_amdgcn_mfma_f32_16x16x32_bf16(a_hi[rt], b_lo, acc[rt][ct], 0, 0, 0);
            }
        }
        __syncthreads();
    }
#pragma unroll
    for (int rt = 0; rt < 4; ++rt)
#pragma unroll
        for (int ct = 0; ct < 3; ++ct)
#pragma unroll
            for (int r = 0; r < 4; ++r) {
                size_t idx = (size_t)(row0 + rt * 16 + q * 4 + r) * N + col0 + wave * 48 + ct * 16 + m;
                Cbfb[idx] = (unsigned short)f2bf(acc[rt][ct][r]);
            }
}

// ---------------- GAT pieces (branch-fused; h in bf16) ----------------
__global__ void gat_elr(const unsigned short* __restrict__ h, const float* __restrict__ al,
                        const float* __restrict__ ar, float* __restrict__ el,
                        float* __restrict__ er, int N, int H, int D,
                        size_t hBr, size_t eBr) {
    int wid = (blockIdx.x * blockDim.x + threadIdx.x) >> 6;
    int lane = threadIdx.x & 63;
    if (wid >= 2 * N * H) return;
    int br = wid / (N * H);
    int loc = wid - br * N * H;
    int n = loc / H, hh = loc - n * H;
    const unsigned short* hp = h + br * hBr + ((size_t)n * H + hh) * D;
    const float* alp = al + (size_t)hh * D;
    const float* arp = ar + (size_t)hh * D;
    float sl = 0.f, sr = 0.f;
    for (int d = lane; d < D; d += 64) {
        float v = us2f(hp[d]);
        sl += v * alp[d];
        sr += v * arp[d];
    }
    for (int off = 32; off > 0; off >>= 1) {
        sl += __shfl_down(sl, off, 64);
        sr += __shfl_down(sr, off, 64);
    }
    if (lane == 0) { el[br * eBr + loc] = sl; er[br * eBr + loc] = sr; }
}

__device__ __forceinline__ float lrelu(float v) {
    return (v > 0.f) ? v : NEG_SLOPE * v;
}

// ---------------- fused softmax + aggregate (block per node) ----------------
#define TILE_E 64
__global__ void gat_softagg(const unsigned short* __restrict__ hb_all,
                            const float* __restrict__ el_all, const float* __restrict__ er_all,
                            const int* __restrict__ src0, const int* __restrict__ src1,
                            const int* __restrict__ rs_all, const int* __restrict__ eidx_all,
                            float4* __restrict__ out4_all, int N, int H, int D, int E,
                            size_t hBr, size_t eBr, size_t o4Br) {
    __shared__ int s_src[TILE_E];
    __shared__ float s_alpha[TILE_E * 3];
    __shared__ float s_stat[6];
    int n = blockIdx.x;
    int br = blockIdx.y;
    const int* src = br ? src1 : src0;
    const int* rs = rs_all + br * (N + 1);
    const int* eidx = eidx_all + br * E;
    const unsigned short* hb = hb_all + br * hBr;
    const float* el = el_all + br * eBr;
    const float* er = er_all + br * eBr;
    float4* out4 = out4_all + br * o4Br;
    int HD = H * D;
    int HD4 = HD >> 2;
    int tid = threadIdx.x;
    int s0 = rs[n], s1 = rs[n + 1];
    int deg = s1 - s0;
    bool activeC = tid < HD4;
    int hh = activeC ? (tid << 2) / D : 0;
    float4 accA = {0.f, 0.f, 0.f, 0.f};
    float4 accB = {0.f, 0.f, 0.f, 0.f};

    if (deg > 0 && deg <= 64) {
        if (tid < 64) {
            int lane = tid;
            float ern0 = er[n * H + 0];
            float ern1 = (H > 1) ? er[n * H + 1] : 0.f;
            float ern2 = (H > 2) ? er[n * H + 2] : 0.f;
            int s = 0;
            float v0 = -INFINITY, v1 = -INFINITY, v2 = -INFINITY;
            if (lane < deg) {
                int e = eidx[s0 + lane];
                s = src[e];
                v0 = lrelu(el[s * H + 0] + ern0);
                if (H > 1) {
                    v1 = lrelu(el[s * H + 1] + ern1);
                    v2 = lrelu(el[s * H + 2] + ern2);
                }
            }
            float m0 = v0, m1 = v1, m2 = v2;
#pragma unroll
            for (int off = 32; off > 0; off >>= 1) {
                m0 = fmaxf(m0, __shfl_xor(m0, off, 64));
                m1 = fmaxf(m1, __shfl_xor(m1, off, 64));
                m2 = fmaxf(m2, __shfl_xor(m2, off, 64));
            }
            float ex0 = (lane < deg) ? expf(v0 - m0) : 0.f;
            float ex1 = (lane < deg && H > 1) ? expf(v1 - m1) : 0.f;
            float ex2 = (lane < deg && H > 2) ? expf(v2 - m2) : 0.f;
            float d0 = ex0, d1 = ex1, d2 = ex2;
#pragma unroll
            for (int off = 32; off > 0; off >>= 1) {
                d0 += __shfl_xor(d0, off, 64);
                d1 += __shfl_xor(d1, off, 64);
                d2 += __shfl_xor(d2, off, 64);
            }
            if (lane < deg) {
                s_src[lane] = s;
                s_alpha[lane * 3 + 0] = ex0 / d0;
                if (H > 1) {
                    s_alpha[lane * 3 + 1] = ex1 / d1;
                    s_alpha[lane * 3 + 2] = ex2 / d2;
                }
            }
        }
        __syncthreads();
        if (activeC) {
            int i = 0;
#pragma unroll 4
            for (; i + 1 < deg; i += 2) {
                float a0 = s_alpha[i * 3 + hh];
                float a1 = s_alpha[(i + 1) * 3 + hh];
                ushort4 h0 = *(const ushort4*)&hb[(size_t)s_src[i] * HD + (tid << 2)];
                ushort4 h1 = *(const ushort4*)&hb[(size_t)s_src[i + 1] * HD + (tid << 2)];
                accA.x += a0 * us2f(h0.x); accA.y += a0 * us2f(h0.y);
                accA.z += a0 * us2f(h0.z); accA.w += a0 * us2f(h0.w);
                accB.x += a1 * us2f(h1.x); accB.y += a1 * us2f(h1.y);
                accB.z += a1 * us2f(h1.z); accB.w += a1 * us2f(h1.w);
            }
            if (i < deg) {
                float a0 = s_alpha[i * 3 + hh];
                ushort4 h0 = *(const ushort4*)&hb[(size_t)s_src[i] * HD + (tid << 2)];
                accA.x += a0 * us2f(h0.x); accA.y += a0 * us2f(h0.y);
                accA.z += a0 * us2f(h0.z); accA.w += a0 * us2f(h0.w);
            }
        }
    } else if (deg > 64) {
        if (tid < 64) {
            int lane = tid;
            float ern0 = er[n * H + 0];
            float ern1 = (H > 1) ? er[n * H + 1] : 0.f;
            float ern2 = (H > 2) ? er[n * H + 2] : 0.f;
            float m0 = -INFINITY, m1 = -INFINITY, m2 = -INFINITY;
            for (int j = s0 + lane; j < s1; j += 64) {
                int e = eidx[j], s = src[e];
                m0 = fmaxf(m0, lrelu(el[s * H + 0] + ern0));
                if (H > 1) {
                    m1 = fmaxf(m1, lrelu(el[s * H + 1] + ern1));
                    m2 = fmaxf(m2, lrelu(el[s * H + 2] + ern2));
                }
            }
#pragma unroll
            for (int off = 32; off > 0; off >>= 1) {
                m0 = fmaxf(m0, __shfl_xor(m0, off, 64));
                m1 = fmaxf(m1, __shfl_xor(m1, off, 64));
                m2 = fmaxf(m2, __shfl_xor(m2, off, 64));
            }
            float d0 = 0.f, d1 = 0.f, d2 = 0.f;
            for (int j = s0 + lane; j < s1; j += 64) {
                int e = eidx[j], s = src[e];
                d0 += expf(lrelu(el[s * H + 0] + ern0) - m0);
                if (H > 1) {
                    d1 += expf(lrelu(el[s * H + 1] + ern1) - m1);
                    d2 += expf(lrelu(el[s * H + 2] + ern2) - m2);
                }
            }
#pragma unroll
            for (int off = 32; off > 0; off >>= 1) {
                d0 += __shfl_xor(d0, off, 64);
                d1 += __shfl_xor(d1, off, 64);
                d2 += __shfl_xor(d2, off, 64);
            }
            if (lane == 0) {
                s_stat[0] = m0; s_stat[1] = m1; s_stat[2] = m2;
                s_stat[3] = 1.f / d0;
                s_stat[4] = (H > 1) ? 1.f / d1 : 0.f;
                s_stat[5] = (H > 2) ? 1.f / d2 : 0.f;
            }
        }
        __syncthreads();
        float m0 = s_stat[0], m1 = s_stat[1], m2 = s_stat[2];
        float i0 = s_stat[3], i1 = s_stat[4], i2 = s_stat[5];
        for (int base = s0; base < s1; base += TILE_E) {
            int cnt = s1 - base; if (cnt > TILE_E) cnt = TILE_E;
            __syncthreads();
            if (tid < cnt) {
                int e = eidx[base + tid], s = src[e];
                s_src[tid] = s;
                s_alpha[tid * 3 + 0] = expf(lrelu(el[s * H + 0] + er[n * H + 0]) - m0) * i0;
                if (H > 1) {
                    s_alpha[tid * 3 + 1] = expf(lrelu(el[s * H + 1] + er[n * H + 1]) - m1) * i1;
                    s_alpha[tid * 3 + 2] = expf(lrelu(el[s * H + 2] + er[n * H + 2]) - m2) * i2;
                }
            }
            __syncthreads();
            if (activeC) {
                int i = 0;
#pragma unroll 2
                for (; i + 1 < cnt; i += 2) {
                    float a0 = s_alpha[i * 3 + hh];
                    float a1 = s_alpha[(i + 1) * 3 + hh];
                    ushort4 h0 = *(const ushort4*)&hb[(size_t)s_src[i] * HD + (tid << 2)];
                    ushort4 h1 = *(const ushort4*)&hb[(size_t)s_src[i + 1] * HD + (tid << 2)];
                    accA.x += a0 * us2f(h0.x); accA.y += a0 * us2f(h0.y);
                    accA.z += a0 * us2f(h0.z); accA.w += a0 * us2f(h0.w);
                    accB.x += a1 * us2f(h1.x); accB.y += a1 * us2f(h1.y);
                    accB.z += a1 * us2f(h1.z); accB.w += a1 * us2f(h1.w);
                }
                if (i < cnt) {
                    float a0 = s_alpha[i * 3 + hh];
                    ushort4 h0 = *(const ushort4*)&hb[(size_t)s_src[i] * HD + (tid << 2)];
                    accA.x += a0 * us2f(h0.x); accA.y += a0 * us2f(h0.y);
                    accA.z += a0 * us2f(h0.z); accA.w += a0 * us2f(h0.w);
                }
            }
        }
    }
    if (activeC) {
        float4 acc;
        acc.x = fmaxf(accA.x + accB.x, 0.f);
        acc.y = fmaxf(accA.y + accB.y, 0.f);
        acc.z = fmaxf(accA.z + accB.z, 0.f);
        acc.w = fmaxf(accA.w + accB.w, 0.f);
        out4[(size_t)n * HD4 + tid] = acc;
    }
}

// Graph max-readout (post-ReLU >=0) via int-bitcast atomicMax. grid.y = branch.
__global__ void seg_max_atomic(const float* __restrict__ g_all, const int* __restrict__ nid,
                               int* __restrict__ out_all, int N, int C,
                               size_t gBr, size_t oBr) {
    int br = blockIdx.y;
    const float* g = g_all + br * gBr;
    int* out = out_all + br * oBr;
    int n0 = blockIdx.x << 5;
    int n1 = n0 + 32; if (n1 > N) n1 = N;
    if (n0 >= N) return;
    for (int c = threadIdx.x; c < C; c += blockDim.x) {
        int cur = nid[n0];
        float m = 0.f;
        for (int n = n0; n < n1; ++n) {
            int gid = nid[n];
            if (gid != cur) {
                atomicMax(&out[cur * C + c], __float_as_int(m));
                cur = gid; m = 0.f;
            }
            m = fmaxf(m, g[(size_t)n * C + c]);
        }
        atomicMax(&out[cur * C + c], __float_as_int(m));
    }
}

// ---------------- small dense layers (grid.z = branch; strides may be 0) ----
__global__ void linear_wave(const float* __restrict__ in, const float* __restrict__ W,
                            const float* __restrict__ bias, float* __restrict__ out,
                            int K, int O, int act, size_t inBr, size_t outBr) {
    int o = blockIdx.x * 4 + (threadIdx.x >> 6);
    int b = blockIdx.y;
    int lane = threadIdx.x & 63;
    if (o >= O) return;
    const float* ip = in + blockIdx.z * inBr + (size_t)b * K;
    float acc = 0.f;
    for (int k = lane; k < K; k += 64)
        acc += ip[k] * W[(size_t)k * O + o];
    for (int off = 32; off > 0; off >>= 1)
        acc += __shfl_down(acc, off, 64);
    if (lane == 0) {
        acc += bias[o];
        if (act == 1) acc = fmaxf(acc, 0.f);
        else if (act == 2) acc = 1.f / (1.f + expf(-acc));
        out[blockIdx.z * outBr + (size_t)b * O + o] = acc;
    }
}

// fc1 fused with the branch gate (K = 256 fixed).
__global__ void linear_cat(const float* __restrict__ gvec, const float* __restrict__ sf,
                           const float* __restrict__ w1, const float* __restrict__ W,
                           const float* __restrict__ bias, float* __restrict__ out,
                           int O, int B128) {
    int o = blockIdx.x * 4 + (threadIdx.x >> 6);
    int b = blockIdx.y;
    int lane = threadIdx.x & 63;
    if (o >= 512) return;
    float w = 1.f / (1.f + expf(-w1[0]));
    float acc = 0.f;
    for (int k = lane; k < 256; k += 64) {
        int br = k >> 7, c = k & 127;
        float v = (1.f - w) * gvec[br * B128 + b * 128 + c] + w * sf[br * B128 + b * 128 + c];
        acc += v * W[(size_t)k * 512 + o];
    }
    for (int off = 32; off > 0; off >>= 1)
        acc += __shfl_down(acc, off, 64);
    if (lane == 0)
        out[(size_t)b * 512 + o] = fmaxf(acc + bias[o], 0.f);
    (void)O;
}

// ---------------- conv1d k=3 as MFMA (im2col on the fly) --------------------
// mode 0: direct row-major input (unused now). mode 1: input is previous conv
// output (rows srcLen long); 3-wide max-pool (stride 3) applied inline while
// staging. mode 2: input is pad[b][l][c] (L=1200, C=64); transpose inline.
__global__ __launch_bounds__(256) void conv_mfma(const float* __restrict__ x,
                                                 const float* __restrict__ x1,
                                                 const short* __restrict__ w2,
                                                 const float* __restrict__ bias,
                                                 float* __restrict__ y,
                                                 int Cin, int Lin, int Lout,
                                                 int mode, int srcLen,
                                                 size_t xBr, size_t yBr) {
    extern __shared__ __align__(16) char smem[];
    float* sx = (float*)smem;                          // Cin x 68 fp32
    short* sB = (short*)(smem + (size_t)Cin * 68 * 4); // 128 x 72 shorts
    int Kp = Cin * 3;
    int K2 = Kp * 2;
    int b = blockIdx.y;
    float* yb = y + blockIdx.z * yBr + (size_t)b * 128 * Lout;
    int l0 = blockIdx.x << 6;
    int tid = threadIdx.x;
    int wave = tid >> 6, lane = tid & 63;
    int m = lane & 15, q = lane >> 4;
    int wrow = (wave & 1) << 5;
    int wcol = (wave >> 1) << 6;
    int loadL = Lin - l0; if (loadL > 66) loadL = 66;
    if (mode == 2) {
        // pad layout [b][l][c], C=64: l-major thread map -> coalesced reads
        const float* pb = (blockIdx.z ? x1 : x) + (size_t)b * 1200 * 64;
        for (int t = tid; t < loadL * 64; t += 256) {
            int i = t >> 6, c = t & 63;
            sx[c * 68 + i] = pb[(size_t)(l0 + i) * 64 + c];
        }
    } else if (mode == 1) {
        // pooled staging from previous conv output (k=3, s=3)
        const float* xb = x + blockIdx.z * xBr + (size_t)b * Cin * srcLen;
        for (int t = tid; t < Cin * loadL; t += 256) {
            int c = t / loadL, i = t - c * loadL;
            const float* row = &xb[(size_t)c * srcLen + 3 * (l0 + i)];
            sx[c * 68 + i] = fmaxf(fmaxf(row[0], row[1]), row[2]);
        }
    } else {
        const float* xb = x + blockIdx.z * xBr + (size_t)b * Cin * srcLen;
        for (int t = tid; t < Cin * loadL; t += 256) {
            int c = t / loadL, i = t - c * loadL;
            sx[c * 68 + i] = xb[(size_t)c * srcLen + l0 + i];
        }
    }
    floatx4 acc[2][4];
#pragma unroll
    for (int rt = 0; rt < 2; ++rt)
#pragma unroll
        for (int ct = 0; ct < 4; ++ct) acc[rt][ct] = (floatx4){0.f, 0.f, 0.f, 0.f};

    for (int k0 = 0; k0 < Kp; k0 += 32) {
#pragma unroll
        for (int p = 0; p < 4; ++p) {
            int t = tid + (p << 8);
            int o = t >> 3, slot = t & 7;
            int srcoff = k0 + ((slot & 3) << 3) + ((slot >= 4) ? Kp : 0);
            *(float4*)&sB[o * 72 + (slot << 3)] = *(const float4*)&w2[(size_t)o * K2 + srcoff];
        }
        __syncthreads();
        short8 a_hi[2], a_lo[2];
#pragma unroll
        for (int rt = 0; rt < 2; ++rt) {
            int pos = wrow + rt * 16 + m;
#pragma unroll
            for (int kk = 0; kk < 8; ++kk) {
                int k = k0 + q * 8 + kk;
                int c = k / 3, j = k - c * 3;
                float v = sx[c * 68 + pos + j];
                short hv = f2bf(v);
                a_hi[rt][kk] = hv;
                a_lo[rt][kk] = f2bf(v - bf2f(hv));
            }
        }
#pragma unroll
        for (int ct = 0; ct < 4; ++ct) {
            short8 b_hi = *(const short8*)&sB[(wcol + ct * 16 + m) * 72 + q * 8];
            short8 b_lo = *(const short8*)&sB[(wcol + ct * 16 + m) * 72 + 32 + q * 8];
#pragma unroll
            for (int rt = 0; rt < 2; ++rt) {
                acc[rt][ct] = __builtin_amdgcn_mfma_f32_16x16x32_bf16(a_hi[rt], b_hi, acc[rt][ct], 0, 0, 0);
                acc[rt][ct] = __builtin_amdgcn_mfma_f32_16x16x32_bf16(a_lo[rt], b_hi, acc[rt][ct], 0, 0, 0);
                acc[rt][ct] = __builtin_amdgcn_mfma_f32_16x16x32_bf16(a_hi[rt], b_lo, acc[rt][ct], 0, 0, 0);
            }
        }
        __syncthreads();
    }
#pragma unroll
    for (int ct = 0; ct < 4; ++ct) {
        int o = wcol + ct * 16 + m;
        float bv = bias[o];
#pragma unroll
        for (int rt = 0; rt < 2; ++rt)
#pragma unroll
            for (int r = 0; r < 4; ++r) {
                int pos = wrow + rt * 16 + q * 4 + r;
                if (l0 + pos < Lout)
                    yb[(size_t)o * Lout + l0 + pos] = acc[rt][ct][r] + bv;
            }
    }
}

// fused: global 130-max-pool over y3 + tf linear + ReLU. block per (b, br).
__global__ void pooltf(const float* __restrict__ y3, const float* __restrict__ tf_w,
                       const float* __restrict__ tf_b, float* __restrict__ sf,
                       size_t yBr, size_t sfBr) {
    __shared__ float s_sp[128];
    int b = blockIdx.x, br = blockIdx.y;
    const float* yb = y3 + br * yBr + (size_t)b * 128 * 130;
    int c = threadIdx.x;
    float mx = -INFINITY;
    for (int l = 0; l < 130; ++l) mx = fmaxf(mx, yb[(size_t)c * 130 + l]);
    s_sp[c] = mx;
    __syncthreads();
    int o = threadIdx.x;
    float acc = tf_b[o];
    for (int k = 0; k < 128; ++k) acc += s_sp[k] * tf_w[(size_t)k * 128 + o];
    sf[br * sfBr + (size_t)b * 128 + o] = fmaxf(acc, 0.f);
}

// ---------------- host ----------------
extern "C" void kernel_launch(void* const* d_in, const int* in_sizes, int n_in,
                              void* d_out, int out_size, void* d_ws, size_t ws_size,
                              hipStream_t stream) {
    const float* feat[2] = {(const float*)d_in[0], (const float*)d_in[1]};
    const float* pad[2]  = {(const float*)d_in[2], (const float*)d_in[3]};
    const int* src[2]    = {(const int*)d_in[4], (const int*)d_in[6]};
    const int* dst[2]    = {(const int*)d_in[5], (const int*)d_in[7]};
    const int* nid[2]    = {(const int*)d_in[8], (const int*)d_in[9]};
    const float* Wg[3]   = {(const float*)d_in[11], (const float*)d_in[14], (const float*)d_in[17]};
    const float* al[3]   = {(const float*)d_in[12], (const float*)d_in[15], (const float*)d_in[18]};
    const float* ar[3]   = {(const float*)d_in[13], (const float*)d_in[16], (const float*)d_in[19]};
    const float* fcg_w = (const float*)d_in[20]; const float* fcg_b = (const float*)d_in[21];
    const float* c1w = (const float*)d_in[22];   const float* c1b = (const float*)d_in[23];
    const float* c2w = (const float*)d_in[24];   const float* c2b = (const float*)d_in[25];
    const float* c3w = (const float*)d_in[26];   const float* c3b = (const float*)d_in[27];
    const float* tf_w = (const float*)d_in[28];  const float* tf_b = (const float*)d_in[29];
    const float* w1 = (const float*)d_in[30];
    const float* fc1_w = (const float*)d_in[31]; const float* fc1_b = (const float*)d_in[32];
    const float* fc2_w = (const float*)d_in[33]; const float* fc2_b = (const float*)d_in[34];
    const float* outw = (const float*)d_in[35];  const float* outb = (const float*)d_in[36];
    float* out = (float*)d_out;

    const int N = in_sizes[0] / 64;   // 8000
    const int E = in_sizes[4];        // 160000
    const int B = 16, L = 1200;
    const size_t NS = (size_t)N * 576;

    char* wsb = (char*)d_ws;
    size_t off = 0;
    auto allocB = [&](size_t bytes) -> void* {
        void* p = wsb + off;
        off += (bytes + 255) & ~(size_t)255;
        return p;
    };
    auto alloc = [&](size_t elems) -> void* { return allocB(elems * 4); };

    unsigned short* h_bf = (unsigned short*)allocB(2 * NS * 2);
    float* gA    = (float*)alloc(2 * NS);
    float* el    = (float*)alloc(2 * (size_t)N * 3);
    float* er    = (float*)alloc(2 * (size_t)N * 3);
    int* rs      = (int*)alloc(2 * (N + 1));
    int* cnt     = (int*)alloc(2 * N);
    int* eidx    = (int*)alloc(2 * E);
    int* gmax    = (int*)alloc(2 * (size_t)B * 576);
    float* gvec  = (float*)alloc(2 * (size_t)B * 128);
    float* sf    = (float*)alloc(2 * (size_t)B * 128);
    float* f1    = (float*)alloc((size_t)B * 512);
    float* f2    = (float*)alloc((size_t)B * 256);
    short* w2t1  = (short*)allocB((size_t)192 * 2 * 64 * 2);
    short* w2t2  = (short*)allocB((size_t)576 * 2 * 192 * 2);
    short* w2t3  = (short*)allocB((size_t)576 * 2 * 576 * 2);
    short* cw1   = (short*)allocB((size_t)128 * 2 * 192 * 2);
    short* cw2   = (short*)allocB((size_t)128 * 2 * 384 * 2);
    short* cw3   = (short*)allocB((size_t)128 * 2 * 384 * 2);
    // UNION: gB aliases TextCNN scratch (y1,y2,y3 only; no xT/p1/p2 anymore)
    size_t tcnn_elems = 2 * (size_t)B * 128 * (1198 + 397 + 130);
    size_t uni_elems = 2 * NS > tcnn_elems ? 2 * NS : tcnn_elems;
    float* uni = (float*)alloc(uni_elems);
    float* gB = uni;
    float* y1 = uni;
    float* y2 = y1 + 2 * (size_t)B * 128 * 1198;
    float* y3 = y2 + 2 * (size_t)B * 128 * 397;
    (void)ws_size; (void)n_in; (void)out_size;

    prep_weights<<<2256, 256, 0, stream>>>(Wg[0], Wg[1], Wg[2], c1w, c2w, c3w,
                                           w2t1, w2t2, w2t3, cw1, cw2, cw3);
    short* w2t[3] = {w2t1, w2t2, w2t3};

    // --- CSR for both branches (scan zeroes cnt for reuse as fill) ---
    zero_i32<<<(2 * N + 255) / 256, 256, 0, stream>>>(cnt, 2 * N);
    count_edges2<<<(2 * E + 255) / 256, 256, 0, stream>>>(dst[0], dst[1], cnt, N, E);
    scan_block<<<2, 1024, 0, stream>>>(cnt, rs, N);
    scatter_edges2<<<(2 * E + 255) / 256, 256, 0, stream>>>(dst[0], dst[1], rs, cnt, eidx, N, E);

    // --- 3 GAT layers, both branches per dispatch ---
    const int dims[3][3] = {{64, 3, 64}, {192, 3, 192}, {576, 1, 576}};
    float* outs[3] = {gA, gB, gA};
    const float* inp0 = feat[0];
    const float* inp1 = feat[1];
    for (int ly = 0; ly < 3; ++ly) {
        int K = dims[ly][0], H = dims[ly][1], D = dims[ly][2];
        int HD = H * D;
        gemm_bf3_v4<<<dim3(HD / 192, N / 64, 2), 256, 0, stream>>>(inp0, inp1, w2t[ly], h_bf,
                                                                   N, K, HD, NS);
        int waves2 = 2 * N * H;
        gat_elr<<<((size_t)waves2 * 64 + 255) / 256, 256, 0, stream>>>(h_bf, al[ly], ar[ly], el, er,
                                                                       N, H, D, NS, (size_t)N * 3);
        int aggThreads = (((HD >> 2) + 63) / 64) * 64;
        gat_softagg<<<dim3(N, 2), aggThreads, 0, stream>>>(
            h_bf, el, er, src[0], src[1], rs, eidx, (float4*)outs[ly],
            N, H, D, E, NS, (size_t)N * 3, NS / 4);
        inp0 = outs[ly];
        inp1 = outs[ly] + NS;
    }
    zero_i32<<<(2 * B * 576 + 255) / 256, 256, 0, stream>>>(gmax, 2 * B * 576);
    seg_max_atomic<<<dim3((N + 31) / 32, 2), 256, 0, stream>>>(gA, nid[0], gmax, N, 576,
                                                               NS, (size_t)B * 576);
    linear_wave<<<dim3(32, B, 2), 256, 0, stream>>>((const float*)gmax, fcg_w, fcg_b, gvec,
                                                    576, 128, 1, (size_t)B * 576, (size_t)B * 128);

    // --- TextCNN (MFMA convs; transpose / pools fused into staging) ---
    conv_mfma<<<dim3(19, B, 2), 256, 64 * 68 * 4 + 128 * 72 * 2, stream>>>(
        pad[0], pad[1], cw1, c1b, y1, 64, 1200, 1198, 2, 0,
        0, (size_t)B * 128 * 1198);
    conv_mfma<<<dim3(7, B, 2), 256, 128 * 68 * 4 + 128 * 72 * 2, stream>>>(
        y1, nullptr, cw2, c2b, y2, 128, 399, 397, 1, 1198,
        (size_t)B * 128 * 1198, (size_t)B * 128 * 397);
    conv_mfma<<<dim3(3, B, 2), 256, 128 * 68 * 4 + 128 * 72 * 2, stream>>>(
        y2, nullptr, cw3, c3b, y3, 128, 132, 130, 1, 397,
        (size_t)B * 128 * 397, (size_t)B * 128 * 130);
    pooltf<<<dim3(B, 2), 128, 0, stream>>>(y3, tf_w, tf_b, sf,
                                           (size_t)B * 128 * 130, (size_t)B * 128);

    // --- head MLP (fc1 fused with branch gate) ---
    linear_cat<<<dim3(128, B, 1), 256, 0, stream>>>(gvec, sf, w1, fc1_w, fc1_b, f1, 512, B * 128);
    linear_wave<<<dim3(64, B, 1), 256, 0, stream>>>(f1, fc2_w, fc2_b, f2, 512, 256, 1, 0, 0);
    linear_wave<<<dim3(1, B, 1), 256, 0, stream>>>(f2, outw, outb, out, 256, 1, 2, 0, 0);
}